// Round 7
// baseline (202.597 us; speedup 1.0000x reference)
//
#include <hip/hip_runtime.h>
#include <math.h>

#define Bn 4096
#define Tn 40
#define Hn 128
#define NGRID 100
#define PI_F 3.14159265358979f
#define SQRT_2PI_F 2.50662827f
#define LOG2E 1.44269504088896f

typedef _Float16 f16;
typedef __attribute__((ext_vector_type(8))) _Float16 f16x8;
typedef __attribute__((ext_vector_type(4))) float f32x4;

// Pin a weight fragment to the AGPR file at this program point (volatile ->
// cannot be hoisted; value stays AGPR-resident across the t-loop, freeing
// arch VGPRs whose budget the RA caps at 128 for this kernel).
#define PIN_A(v) asm volatile("" : "+a"(v))

struct GruW {
  const f16 *fWhh0, *fWih1, *fWhh1;     // fragment-layout fp16, gate-scaled
  const float *Wih0, *bih0, *bhh0, *bih1, *bhh1, *Wh, *bh;
};
struct WSrc { const float* m[6]; };

__device__ __forceinline__ float rcp_f(float x){ return __builtin_amdgcn_rcpf(x); }
__device__ __forceinline__ float ex2(float x){ return __builtin_amdgcn_exp2f(x); }

// ---- fp32 [384][128] -> fp16 MFMA-B fragment layout, pre-scaled per gate:
//      r,z rows (n<256): * -log2e ; n rows (n>=256): * 2*log2e
__global__ __launch_bounds__(256)
void wconv_k(WSrc S, f16* __restrict__ dst)
{
  const int m  = blockIdx.x / 24;
  const int nt = blockIdx.x % 24;
  const int ks = threadIdx.x >> 6;
  const int l  = threadIdx.x & 63;
  const float scale = (nt < 16) ? -LOG2E : (2.0f*LOG2E);
  const float* src = S.m[m] + (size_t)(nt*16 + (l&15))*Hn + ks*32 + (l>>4)*8;
  f16x8 o;
  #pragma unroll
  for (int jj = 0; jj < 8; ++jj) o[jj] = (f16)(src[jj] * scale);
  *((f16x8*)(dst + (size_t)m*49152) + ((nt*4 + ks)*64 + l)) = o;
}

// ---- fused 2-layer GRU; weights AGPR-resident; two compute phases per step.
__global__ __launch_bounds__(512)
void gru_mfma(const float* __restrict__ x, GruW Wd, GruW Ws,
              float* __restrict__ mu_out, float* __restrict__ sig_out)
{
  const int net = blockIdx.x >> 7;
  const int r0  = (blockIdx.x & 127) * 32;
  const GruW W  = net ? Ws : Wd;
  const int tid = threadIdx.x;
  const int w   = tid >> 6;        // wave 0..7 -> gate-col block w*16..+15
  const int l   = tid & 63;

  __shared__ __align__(16) char smem[40960];
  char* const h0b0 = smem;                 // [32][128] f16, swizzled (8KB each)
  char* const h0b1 = smem + 8192;
  char* const h1b0 = smem + 16384;
  char* const h1b1 = smem + 24576;
  float* const xall = (float*)(smem + 32768);   // [32][40] f32

  for (int i = tid; i < 32*Tn; i += 512) xall[i] = x[(size_t)r0*Tn + i];
  ((int4*)h1b1)[tid] = make_int4(0,0,0,0);

  const int j = w*16 + (l & 15);   // hidden column 0..127
  const float wr_s = W.Wih0[j]      * (-LOG2E);
  const float wz_s = W.Wih0[Hn+j]   * (-LOG2E);
  const float wn_s = W.Wih0[2*Hn+j] * (2.0f*LOG2E);
  const float br0_s  = (W.bih0[j]      + W.bhh0[j])      * (-LOG2E);
  const float bz0_s  = (W.bih0[Hn+j]   + W.bhh0[Hn+j])   * (-LOG2E);
  const float bin0_s = W.bih0[2*Hn+j] * (2.0f*LOG2E);
  const float bnh0_s = W.bhh0[2*Hn+j] * (2.0f*LOG2E);
  const float br1_s  = (W.bih1[j]      + W.bhh1[j])      * (-LOG2E);
  const float bz1_s  = (W.bih1[Hn+j]   + W.bhh1[Hn+j])   * (-LOG2E);
  const float bin1_s = W.bih1[2*Hn+j] * (2.0f*LOG2E);
  const float bnh1_s = W.bhh1[2*Hn+j] * (2.0f*LOG2E);

  // weight fragments -> loaded once, pinned into AGPRs inside the loop
  const f16x8* F0  = (const f16x8*)W.fWhh0;
  const f16x8* F1i = (const f16x8*)W.fWih1;
  const f16x8* F1h = (const f16x8*)W.fWhh1;
  f16x8 w0[3][4], w1i[3][4], w1h[3][4];
  #pragma unroll
  for (int g = 0; g < 3; ++g)
    #pragma unroll
    for (int ks = 0; ks < 4; ++ks) {
      const int idx = ((w + 8*g)*4 + ks)*64 + l;
      w0[g][ks]  = F0[idx];
      w1i[g][ks] = F1i[idx];
      w1h[g][ks] = F1h[idx];
    }

  const int ar   = l & 15;
  const int msk  = (ar & 7) << 4;
  const int acol = (l >> 4) * 16;
  const int abase = ar * 256;
  const int xb = (l>>4)*4*Tn;
  const int j2 = j*2;

  float h0r[8], h1r[8] = {0,0,0,0,0,0,0,0}, s1r[8] = {0,0,0,0,0,0,0,0};

  __syncthreads();   // xall + h1b1 ready

  // ---- prologue: h0(0) from x(0) only (h0(-1)=0)
  #pragma unroll
  for (int mt = 0; mt < 2; ++mt)
    #pragma unroll
    for (int q = 0; q < 4; ++q) {
      const int row = mt*16 + (l>>4)*4 + q;
      const float xv = xall[xb + mt*16*Tn + q*Tn];
      const float rg = rcp_f(1.f + ex2(fmaf(xv, wr_s, br0_s)));
      const float zg = rcp_f(1.f + ex2(fmaf(xv, wz_s, bz0_s)));
      const float xn = fmaf(xv, wn_s, bin0_s);
      const float ng = fmaf(rcp_f(1.f + ex2(fmaf(rg, bnh0_s, xn))), -2.f, 1.f);
      const float hv = fmaf(-zg, ng, ng);
      h0r[mt*4+q] = hv;
      *(f16*)(h0b0 + row*256 + (j2 ^ ((row & 7) << 4))) = (f16)hv;
    }
  __syncthreads();

  for (int i = 0; i < Tn; ++i) {
    const char* h0cur = (i&1) ? h0b1 : h0b0;
    char*       h0nxt = (i&1) ? h0b0 : h0b1;
    const char* h1prv = (i&1) ? h1b0 : h1b1;
    char*       h1cur = (i&1) ? h1b1 : h1b0;

    // ================= phase L0: gh0 = h0(i) @ Whh0^T -> h0(i+1) ============
    {
      f32x4 aR[2], aZ[2], aN[2];
      #pragma unroll
      for (int mt = 0; mt < 2; ++mt) {
        aR[mt] = (f32x4){br0_s,br0_s,br0_s,br0_s};
        aZ[mt] = (f32x4){bz0_s,bz0_s,bz0_s,bz0_s};
        aN[mt] = (f32x4){bnh0_s,bnh0_s,bnh0_s,bnh0_s};
      }
      #pragma unroll
      for (int ks = 0; ks < 4; ++ks) {
        const int kc = (ks*64 + acol) ^ msk;
        const f16x8 a0 = *(const f16x8*)(h0cur + abase + kc);
        const f16x8 a1 = *(const f16x8*)(h0cur + abase + 4096 + kc);
        PIN_A(w0[0][ks]); PIN_A(w0[1][ks]); PIN_A(w0[2][ks]);
        aR[0] = __builtin_amdgcn_mfma_f32_16x16x32_f16(a0, w0[0][ks], aR[0], 0,0,0);
        aR[1] = __builtin_amdgcn_mfma_f32_16x16x32_f16(a1, w0[0][ks], aR[1], 0,0,0);
        aZ[0] = __builtin_amdgcn_mfma_f32_16x16x32_f16(a0, w0[1][ks], aZ[0], 0,0,0);
        aZ[1] = __builtin_amdgcn_mfma_f32_16x16x32_f16(a1, w0[1][ks], aZ[1], 0,0,0);
        aN[0] = __builtin_amdgcn_mfma_f32_16x16x32_f16(a0, w0[2][ks], aN[0], 0,0,0);
        aN[1] = __builtin_amdgcn_mfma_f32_16x16x32_f16(a1, w0[2][ks], aN[1], 0,0,0);
      }
      if (i < Tn-1) {
        #pragma unroll
        for (int mt = 0; mt < 2; ++mt)
          #pragma unroll
          for (int q = 0; q < 4; ++q) {
            const int e = mt*4+q;
            const int row = mt*16 + (l>>4)*4 + q;
            const float xv = xall[xb + mt*16*Tn + q*Tn + i + 1];
            const float rg = rcp_f(1.f + ex2(fmaf(xv, wr_s, aR[mt][q])));
            const float zg = rcp_f(1.f + ex2(fmaf(xv, wz_s, aZ[mt][q])));
            const float xn = fmaf(xv, wn_s, bin0_s);
            const float ng = fmaf(rcp_f(1.f + ex2(fmaf(rg, aN[mt][q], xn))), -2.f, 1.f);
            const float hv = fmaf(zg, h0r[e] - ng, ng);
            h0r[e] = hv;
            *(f16*)(h0nxt + row*256 + (j2 ^ ((row & 7) << 4))) = (f16)hv;
          }
      }
    }

    // ================= phase L1: h0(i)@Wih1^T + h1(i-1)@Whh1^T -> h1(i) =====
    {
      f32x4 aR[2], aZ[2], aXN[2], aHN[2];
      #pragma unroll
      for (int mt = 0; mt < 2; ++mt) {
        aR[mt]  = (f32x4){br1_s,br1_s,br1_s,br1_s};
        aZ[mt]  = (f32x4){bz1_s,bz1_s,bz1_s,bz1_s};
        aXN[mt] = (f32x4){bin1_s,bin1_s,bin1_s,bin1_s};
        aHN[mt] = (f32x4){bnh1_s,bnh1_s,bnh1_s,bnh1_s};
      }
      #pragma unroll
      for (int ks = 0; ks < 4; ++ks) {
        const int kc = (ks*64 + acol) ^ msk;
        const f16x8 a0_0 = *(const f16x8*)(h0cur + abase + kc);
        const f16x8 a0_1 = *(const f16x8*)(h0cur + abase + 4096 + kc);
        const f16x8 a1_0 = *(const f16x8*)(h1prv + abase + kc);
        const f16x8 a1_1 = *(const f16x8*)(h1prv + abase + 4096 + kc);
        PIN_A(w1i[0][ks]); PIN_A(w1i[1][ks]); PIN_A(w1i[2][ks]);
        PIN_A(w1h[0][ks]); PIN_A(w1h[1][ks]); PIN_A(w1h[2][ks]);
        aR[0]  = __builtin_amdgcn_mfma_f32_16x16x32_f16(a0_0, w1i[0][ks], aR[0], 0,0,0);
        aR[1]  = __builtin_amdgcn_mfma_f32_16x16x32_f16(a0_1, w1i[0][ks], aR[1], 0,0,0);
        aR[0]  = __builtin_amdgcn_mfma_f32_16x16x32_f16(a1_0, w1h[0][ks], aR[0], 0,0,0);
        aR[1]  = __builtin_amdgcn_mfma_f32_16x16x32_f16(a1_1, w1h[0][ks], aR[1], 0,0,0);
        aZ[0]  = __builtin_amdgcn_mfma_f32_16x16x32_f16(a0_0, w1i[1][ks], aZ[0], 0,0,0);
        aZ[1]  = __builtin_amdgcn_mfma_f32_16x16x32_f16(a0_1, w1i[1][ks], aZ[1], 0,0,0);
        aZ[0]  = __builtin_amdgcn_mfma_f32_16x16x32_f16(a1_0, w1h[1][ks], aZ[0], 0,0,0);
        aZ[1]  = __builtin_amdgcn_mfma_f32_16x16x32_f16(a1_1, w1h[1][ks], aZ[1], 0,0,0);
        aXN[0] = __builtin_amdgcn_mfma_f32_16x16x32_f16(a0_0, w1i[2][ks], aXN[0], 0,0,0);
        aXN[1] = __builtin_amdgcn_mfma_f32_16x16x32_f16(a0_1, w1i[2][ks], aXN[1], 0,0,0);
        aHN[0] = __builtin_amdgcn_mfma_f32_16x16x32_f16(a1_0, w1h[2][ks], aHN[0], 0,0,0);
        aHN[1] = __builtin_amdgcn_mfma_f32_16x16x32_f16(a1_1, w1h[2][ks], aHN[1], 0,0,0);
      }
      #pragma unroll
      for (int mt = 0; mt < 2; ++mt)
        #pragma unroll
        for (int q = 0; q < 4; ++q) {
          const int e = mt*4+q;
          const int row = mt*16 + (l>>4)*4 + q;
          const float rg = rcp_f(1.f + ex2(aR[mt][q]));
          const float zg = rcp_f(1.f + ex2(aZ[mt][q]));
          const float ng = fmaf(rcp_f(1.f + ex2(fmaf(rg, aHN[mt][q], aXN[mt][q]))), -2.f, 1.f);
          const float hv = fmaf(zg, h1r[e] - ng, ng);
          h1r[e] = hv;
          s1r[e] += hv;
          *(f16*)(h1cur + row*256 + (j2 ^ ((row & 7) << 4))) = (f16)hv;
        }
    }
    __syncthreads();   // single barrier per step
  }

  // ---- head: p[row] = h0.WhA + h1.WhB + mean_t(s1).WhC, reduce over j
  const float whA = W.Wh[j], whB = W.Wh[Hn+j], whC = W.Wh[2*Hn+j] * (1.0f/Tn);
  float* hredf = (float*)h0b0;    // reuse dead buffer: [32][8]
  #pragma unroll
  for (int mt = 0; mt < 2; ++mt)
    #pragma unroll
    for (int q = 0; q < 4; ++q) {
      const int e = mt*4+q;
      float p = h0r[e]*whA + h1r[e]*whB + s1r[e]*whC;
      p += __shfl_xor(p, 1); p += __shfl_xor(p, 2);
      p += __shfl_xor(p, 4); p += __shfl_xor(p, 8);
      if ((l & 15) == 0) hredf[(mt*16 + (l>>4)*4 + q)*8 + w] = p;
    }
  __syncthreads();
  if (tid < 32) {
    float s = W.bh[0];
    #pragma unroll
    for (int ww = 0; ww < 8; ++ww) s += hredf[tid*8 + ww];
    const float v = fminf(fmaxf(s, -20.f), 20.f);
    const int b = r0 + tid;
    if (net == 0) mu_out[b] = v;
    else          sig_out[b] = log1pf(__expf(v)) + 1e-4f;
  }
}

// ---------------- regularized incomplete beta (NR continued fraction) --------
__device__ float betacf_(float a, float b, float x)
{
  const float FPMIN = 1e-30f, EPS = 3e-7f;
  const float qab = a + b, qap = a + 1.f, qam = a - 1.f;
  float c = 1.f;
  float d = 1.f - qab * x / qap;
  if (fabsf(d) < FPMIN) d = FPMIN;
  d = 1.f / d;
  float h = d;
  for (int m = 1; m <= 100; ++m) {
    const float m2 = 2.f * m;
    float aa = m * (b - m) * x / ((qam + m2) * (a + m2));
    d = 1.f + aa * d; if (fabsf(d) < FPMIN) d = FPMIN;
    c = 1.f + aa / c; if (fabsf(c) < FPMIN) c = FPMIN;
    d = 1.f / d; h *= d * c;
    aa = -(a + m) * (qab + m) * x / ((a + m2) * (qap + m2));
    d = 1.f + aa * d; if (fabsf(d) < FPMIN) d = FPMIN;
    c = 1.f + aa / c; if (fabsf(c) < FPMIN) c = FPMIN;
    d = 1.f / d;
    const float del = d * c; h *= del;
    if (fabsf(del - 1.f) < EPS) break;
  }
  return h;
}

__device__ float betainc_(float a, float b, float x, float cx)
{
  if (x  <= 0.f) return 0.f;
  if (cx <= 0.f) return 1.f;
  const float lx  = (x  > 0.5f) ? log1pf(-cx) : logf(x);
  const float lcx = (cx > 0.5f) ? log1pf(-x)  : logf(cx);
  const float bt = expf(lgammaf(a+b) - lgammaf(a) - lgammaf(b) + a*lx + b*lcx);
  if (x < (a + 1.f) / (a + b + 2.f)) return bt * betacf_(a, b, x) / a;
  else                               return 1.f - bt * betacf_(b, a, cx) / b;
}

__global__ __launch_bounds__(256)
void stats_k(const float* __restrict__ mu, const float* __restrict__ sig,
             const float* __restrict__ dX, const float* __restrict__ dTp,
             const float* __restrict__ log_nu,
             float* __restrict__ cdf_out, float* __restrict__ parts)
{
  const int tid = threadIdx.x;
  const int b = blockIdx.x * 256 + tid;
  const float dT = dTp[0];
  const float df = fminf(fmaxf(expf(log_nu[0]), 2.1f), 30.0f);

  const float m = mu[b], s = sig[b];
  const float scale = s * sqrtf(dT);
  const float y  = (dX[b] - m * dT) / scale;
  const float y2 = y * y;
  const float lp = lgammaf((df + 1.f) * 0.5f) - lgammaf(df * 0.5f)
                 - 0.5f * logf(df * PI_F) - logf(scale)
                 - (df + 1.f) * 0.5f * log1pf(y2 / df);
  const float den = df + y2;
  const float xb = df / den, cxb = y2 / den;
  const float ib = betainc_(0.5f * df, 0.5f, xb, cxb);
  float cdf = (y <= 0.f) ? 0.5f * ib : 1.f - 0.5f * ib;
  cdf = fminf(fmaxf(cdf, 1e-6f), 1.f - 1e-6f);
  cdf_out[b] = cdf;

  __shared__ float red[256];
  red[tid] = lp; __syncthreads();
  for (int o = 128; o > 0; o >>= 1) { if (tid < o) red[tid] += red[tid + o]; __syncthreads(); }
  if (tid == 0) parts[blockIdx.x] = red[0];
  __syncthreads();
  red[tid] = cdf; __syncthreads();
  for (int o = 128; o > 0; o >>= 1) { if (tid < o) red[tid] += red[tid + o]; __syncthreads(); }
  if (tid == 0) parts[16 + blockIdx.x] = red[0];
  __syncthreads();
  red[tid] = cdf * cdf; __syncthreads();
  for (int o = 128; o > 0; o >>= 1) { if (tid < o) red[tid] += red[tid + o]; __syncthreads(); }
  if (tid == 0) parts[32 + blockIdx.x] = red[0];
}

// ---------------- KDE: one block per grid point -------------------------------
__global__ __launch_bounds__(256)
void kde_k(const float* __restrict__ cdf, const float* __restrict__ parts,
           float* __restrict__ pen)
{
  const int tid = threadIdx.x;
  float sc = 0.f, sc2 = 0.f;
  #pragma unroll
  for (int i = 0; i < 16; ++i) { sc += parts[16+i]; sc2 += parts[32+i]; }
  const float mean = sc / (float)Bn;
  const float var  = (sc2 - (float)Bn * mean * mean) / (float)(Bn - 1);
  const float sd   = sqrtf(fmaxf(var, 0.f));
  const float hbw  = 1.06f * sd * 0.18946457f + 1e-5f;   // 4096^-0.2
  const float inv  = 1.0f / hbw;
  const float u    = (float)blockIdx.x / (float)(NGRID - 1);
  const float c    = -0.5f * LOG2E;

  float acc = 0.f;
  for (int k = tid; k < Bn; k += 256) {
    const float d = (u - cdf[k]) * inv;
    acc += ex2(d * d * c);
  }
  __shared__ float sh[256];
  sh[tid] = acc; __syncthreads();
  for (int o = 128; o > 0; o >>= 1) { if (tid < o) sh[tid] += sh[tid + o]; __syncthreads(); }
  if (tid == 0) {
    const float f = sh[0] / (SQRT_2PI_F * (float)Bn * hbw);
    const float dd = f - 1.0f;
    pen[blockIdx.x] = dd * dd * (1.0f / (float)NGRID);
  }
}

__global__ __launch_bounds__(128)
void finish_k(const float* __restrict__ parts, const float* __restrict__ pen,
              float* __restrict__ out)
{
  const int tid = threadIdx.x;
  __shared__ float sh[128];
  sh[tid] = (tid < NGRID) ? pen[tid] : 0.f;
  __syncthreads();
  for (int o = 64; o > 0; o >>= 1) { if (tid < o) sh[tid] += sh[tid + o]; __syncthreads(); }
  if (tid == 0) {
    float slp = 0.f;
    #pragma unroll
    for (int i = 0; i < 16; ++i) slp += parts[i];
    out[0] = (-slp / (float)Bn) + 100.0f * sh[0];
  }
}

// ---------------- launcher ---------------------------------------------------
extern "C" void kernel_launch(void* const* d_in, const int* in_sizes, int n_in,
                              void* d_out, int out_size, void* d_ws, size_t ws_size,
                              hipStream_t stream)
{
  const float* x      = (const float*)d_in[0];
  const float* dX     = (const float*)d_in[1];
  const float* dT     = (const float*)d_in[2];
  const float* log_nu = (const float*)d_in[23];

  float* w     = (float*)d_ws;
  float* mu    = w;
  float* sig   = w + Bn;
  float* cdf   = w + 2 * Bn;
  float* parts = w + 3 * Bn;                    // 48 floats
  float* pen   = w + 3 * Bn + 48;               // 100 floats
  f16*  fragb  = (f16*)((char*)d_ws + 65536);   // 6 x 49152 halfs

  WSrc S;
  S.m[0] = (const float*)d_in[4];   // d_Whh0
  S.m[1] = (const float*)d_in[7];   // d_Wih1
  S.m[2] = (const float*)d_in[8];   // d_Whh1
  S.m[3] = (const float*)d_in[14];  // s_Whh0
  S.m[4] = (const float*)d_in[17];  // s_Wih1
  S.m[5] = (const float*)d_in[18];  // s_Whh1

  GruW Wd { fragb + (size_t)0*49152, fragb + (size_t)1*49152, fragb + (size_t)2*49152,
            (const float*)d_in[3], (const float*)d_in[5], (const float*)d_in[6],
            (const float*)d_in[9], (const float*)d_in[10],
            (const float*)d_in[11], (const float*)d_in[12] };
  GruW Ws { fragb + (size_t)3*49152, fragb + (size_t)4*49152, fragb + (size_t)5*49152,
            (const float*)d_in[13], (const float*)d_in[15], (const float*)d_in[16],
            (const float*)d_in[19], (const float*)d_in[20],
            (const float*)d_in[21], (const float*)d_in[22] };

  wconv_k <<<dim3(6*24), 256, 0, stream>>>(S, fragb);
  gru_mfma<<<dim3(256), 512, 0, stream>>>(x, Wd, Ws, mu, sig);
  stats_k <<<dim3(Bn/256), 256, 0, stream>>>(mu, sig, dX, dT, log_nu, cdf, parts);
  kde_k   <<<dim3(NGRID), 256, 0, stream>>>(cdf, parts, pen);
  finish_k<<<dim3(1), 128, 0, stream>>>(parts, pen, (float*)d_out);
}

// Round 8
// 140.421 us; speedup vs baseline: 1.4428x; 1.4428x over previous
//
#include <hip/hip_runtime.h>
#include <math.h>

#define Bn 4096
#define Tn 40
#define Hn 128
#define NGRID 100
#define PI_F 3.14159265358979f
#define SQRT_2PI_F 2.50662827f
#define LOG2E 1.44269504088896f

typedef _Float16 f16;
typedef __attribute__((ext_vector_type(8))) _Float16 f16x8;
typedef __attribute__((ext_vector_type(4))) float f32x4;

// MFMA with weight (B) operand pinned to AGPR class: all uses of the weight
// values are 'a'-class, so the RA homes them in AGPRs (loaded once, read
// directly by MFMA -- gfx950 unified RF allows AGPR B operands).
#define MFMA0(acc, va, wa) \
  asm("v_mfma_f32_16x16x32_f16 %0, %1, %2, 0" : "=v"(acc) : "v"(va), "a"(wa))
#define MFMA(acc, va, wa) \
  asm("v_mfma_f32_16x16x32_f16 %0, %1, %2, %0" : "+v"(acc) : "v"(va), "a"(wa))

struct GruW {
  const f16 *fWhh0, *fWih1, *fWhh1;     // fragment-layout fp16, gate-scaled
  const float *Wih0, *bih0, *bhh0, *bih1, *bhh1, *Wh, *bh;
};
struct WSrc { const float* m[6]; };

__device__ __forceinline__ float rcp_f(float x){ return __builtin_amdgcn_rcpf(x); }
__device__ __forceinline__ float ex2(float x){ return __builtin_amdgcn_exp2f(x); }
// LDS swizzle on byte bits 4..6: reads 2-way (free), writes conflict-free.
__device__ __forceinline__ int swz(int r){
  return ((r&1)<<4) | ((((r>>1)^(r>>3))&1)<<5) | ((r&4)<<4);
}

// ---- fp32 [384][128] -> fp16 MFMA-B fragment layout, pre-scaled per gate:
//      r,z rows (n<256): * -log2e ; n rows (n>=256): * 2*log2e
__global__ __launch_bounds__(256)
void wconv_k(WSrc S, f16* __restrict__ dst)
{
  const int m  = blockIdx.x / 24;
  const int nt = blockIdx.x % 24;
  const int ks = threadIdx.x >> 6;
  const int l  = threadIdx.x & 63;
  const float scale = (nt < 16) ? -LOG2E : (2.0f*LOG2E);
  const float* src = S.m[m] + (size_t)(nt*16 + (l&15))*Hn + ks*32 + (l>>4)*8;
  f16x8 o;
  #pragma unroll
  for (int jj = 0; jj < 8; ++jj) o[jj] = (f16)(src[jj] * scale);
  *((f16x8*)(dst + (size_t)m*49152) + ((nt*4 + ks)*64 + l)) = o;
}

// ---- fused 2-layer GRU: 16 rows/block, 8 waves, weights AGPR-resident.
__global__ __launch_bounds__(512)
void gru_mfma(const float* __restrict__ x, GruW Wd, GruW Ws,
              float* __restrict__ mu_out, float* __restrict__ sig_out)
{
  const int bid = blockIdx.x;
  const int net = bid >> 8;
  const int r0  = (bid & 255) * 16;
  const GruW W  = net ? Ws : Wd;
  const int tid = threadIdx.x;
  const int w   = tid >> 6;        // wave 0..7 -> gate-col block w*16..+15
  const int l   = tid & 63;

  __shared__ __align__(16) char smem[19456];
  char* const h0b0 = smem;                 // [16][128] f16, swizzled (4KB each)
  char* const h0b1 = smem + 4096;
  char* const h1b0 = smem + 8192;
  char* const h1b1 = smem + 12288;
  float* const xall = (float*)(smem + 16384);   // [16][40] f32

  for (int i = tid; i < 16*Tn; i += 512) xall[i] = x[(size_t)r0*Tn + i];
  ((int2*)h1b1)[tid] = make_int2(0,0);

  const int j = w*16 + (l & 15);   // hidden column 0..127
  const float wr_s = W.Wih0[j]      * (-LOG2E);
  const float wz_s = W.Wih0[Hn+j]   * (-LOG2E);
  const float wn_s = W.Wih0[2*Hn+j] * (2.0f*LOG2E);
  const float br0_s  = (W.bih0[j]      + W.bhh0[j])      * (-LOG2E);
  const float bz0_s  = (W.bih0[Hn+j]   + W.bhh0[Hn+j])   * (-LOG2E);
  const float bin0_s = W.bih0[2*Hn+j] * (2.0f*LOG2E);
  const float bnh0_s = W.bhh0[2*Hn+j] * (2.0f*LOG2E);
  const float br1_s  = (W.bih1[j]      + W.bhh1[j])      * (-LOG2E);
  const float bz1_s  = (W.bih1[Hn+j]   + W.bhh1[Hn+j])   * (-LOG2E);
  const float bin1_s = W.bih1[2*Hn+j] * (2.0f*LOG2E);
  const float bnh1_s = W.bhh1[2*Hn+j] * (2.0f*LOG2E);

  // weight fragments: every use below is an 'a'-constrained MFMA operand ->
  // homed in AGPRs (144 AGPRs), arch-VGPR budget stays ~110.
  const f16x8* F0  = (const f16x8*)W.fWhh0;
  const f16x8* F1i = (const f16x8*)W.fWih1;
  const f16x8* F1h = (const f16x8*)W.fWhh1;
  f16x8 w0[3][4], w1i[3][4], w1h[3][4];
  #pragma unroll
  for (int g = 0; g < 3; ++g)
    #pragma unroll
    for (int ks = 0; ks < 4; ++ks) {
      const int idx = ((w + 8*g)*4 + ks)*64 + l;
      w0[g][ks]  = F0[idx];
      w1i[g][ks] = F1i[idx];
      w1h[g][ks] = F1h[idx];
    }

  // A-frag read offsets (swizzled), h write offsets
  int aoff[4], woffq[4];
  {
    const int ar = l & 15, msk = swz(ar), acol = (l >> 4) * 16;
    #pragma unroll
    for (int ks = 0; ks < 4; ++ks)
      aoff[ks] = ar*256 + ((ks*64 + acol) ^ msk);
    #pragma unroll
    for (int q = 0; q < 4; ++q) {
      const int row = (l>>4)*4 + q;
      woffq[q] = row*256 + ((2*j) ^ swz(row));
    }
  }

  float h0r[4], h1r[4] = {0,0,0,0}, s1r[4] = {0,0,0,0};

  __syncthreads();   // xall + h1b1 ready

  // ---- prologue: h0(0) from x(0) only (h0(-1)=0)
  #pragma unroll
  for (int q = 0; q < 4; ++q) {
    const int row = (l>>4)*4 + q;
    const float xv = xall[row*Tn + 0];
    const float rg = rcp_f(1.f + ex2(fmaf(xv, wr_s, br0_s)));
    const float zg = rcp_f(1.f + ex2(fmaf(xv, wz_s, bz0_s)));
    const float xn = fmaf(xv, wn_s, bin0_s);
    const float ng = fmaf(rcp_f(1.f + ex2(fmaf(rg, bnh0_s, xn))), -2.f, 1.f);
    const float hv = fmaf(-zg, ng, ng);
    h0r[q] = hv;
    *(f16*)(h0b0 + woffq[q]) = (f16)hv;
  }
  __syncthreads();

  for (int i = 0; i < Tn; ++i) {
    const char* h0cur = (i&1) ? h0b1 : h0b0;
    char*       h0nxt = (i&1) ? h0b0 : h0b1;
    const char* h1prv = (i&1) ? h1b0 : h1b1;
    char*       h1cur = (i&1) ? h1b1 : h1b0;

    f32x4 aR0, aZ0, aN0, aR1, aZ1, aXN1, aHN1;   // 7 accums = 28 VGPR

    #pragma unroll
    for (int ks = 0; ks < 4; ++ks) {
      const f16x8 a0 = *(const f16x8*)(h0cur + aoff[ks]);
      const f16x8 a1 = *(const f16x8*)(h1prv + aoff[ks]);
      if (ks == 0) {
        MFMA0(aR0,  a0, w0[0][0]);
        MFMA0(aZ0,  a0, w0[1][0]);
        MFMA0(aN0,  a0, w0[2][0]);
        MFMA0(aR1,  a0, w1i[0][0]);
        MFMA0(aZ1,  a0, w1i[1][0]);
        MFMA0(aXN1, a0, w1i[2][0]);
        MFMA (aR1,  a1, w1h[0][0]);
        MFMA (aZ1,  a1, w1h[1][0]);
        MFMA0(aHN1, a1, w1h[2][0]);
      } else {
        MFMA(aR0,  a0, w0[0][ks]);
        MFMA(aZ0,  a0, w0[1][ks]);
        MFMA(aN0,  a0, w0[2][ks]);
        MFMA(aR1,  a0, w1i[0][ks]);
        MFMA(aZ1,  a0, w1i[1][ks]);
        MFMA(aXN1, a0, w1i[2][ks]);
        MFMA(aR1,  a1, w1h[0][ks]);
        MFMA(aZ1,  a1, w1h[1][ks]);
        MFMA(aHN1, a1, w1h[2][ks]);
      }
    }

    // ---- L0 gates for t=i+1 -> h0(i+1)   (bias folded back in VALU)
    if (i < Tn-1) {
      #pragma unroll
      for (int q = 0; q < 4; ++q) {
        const int row = (l>>4)*4 + q;
        const float xv = xall[row*Tn + i + 1];
        const float rg = rcp_f(1.f + ex2(fmaf(xv, wr_s, br0_s) + aR0[q]));
        const float zg = rcp_f(1.f + ex2(fmaf(xv, wz_s, bz0_s) + aZ0[q]));
        const float xn = fmaf(xv, wn_s, bin0_s);
        const float ng = fmaf(rcp_f(1.f + ex2(fmaf(rg, aN0[q] + bnh0_s, xn))), -2.f, 1.f);
        const float hv = fmaf(zg, h0r[q] - ng, ng);
        h0r[q] = hv;
        *(f16*)(h0nxt + woffq[q]) = (f16)hv;
      }
    }
    // ---- L1 gates for t=i -> h1(i)
    #pragma unroll
    for (int q = 0; q < 4; ++q) {
      const float rg = rcp_f(1.f + ex2(aR1[q] + br1_s));
      const float zg = rcp_f(1.f + ex2(aZ1[q] + bz1_s));
      const float ng = fmaf(rcp_f(1.f + ex2(fmaf(rg, aHN1[q] + bnh1_s, aXN1[q] + bin1_s))), -2.f, 1.f);
      const float hv = fmaf(zg, h1r[q] - ng, ng);
      h1r[q] = hv;
      s1r[q] += hv;
      *(f16*)(h1cur + woffq[q]) = (f16)hv;
    }
    __syncthreads();   // single barrier per step
  }

  // ---- head: p[row] = h0.WhA + h1.WhB + mean_t(s1).WhC, reduce over j
  const float whA = W.Wh[j], whB = W.Wh[Hn+j], whC = W.Wh[2*Hn+j] * (1.0f/Tn);
  float* hredf = (float*)h0b0;    // reuse dead buffer: [16][8]
  #pragma unroll
  for (int q = 0; q < 4; ++q) {
    const int row = (l>>4)*4 + q;
    float p = h0r[q]*whA + h1r[q]*whB + s1r[q]*whC;
    p += __shfl_xor(p, 1); p += __shfl_xor(p, 2);
    p += __shfl_xor(p, 4); p += __shfl_xor(p, 8);
    if ((l & 15) == 0) hredf[row*8 + w] = p;
  }
  __syncthreads();
  if (tid < 16) {
    float s = W.bh[0];
    #pragma unroll
    for (int ww = 0; ww < 8; ++ww) s += hredf[tid*8 + ww];
    const float v = fminf(fmaxf(s, -20.f), 20.f);
    const int b = r0 + tid;
    if (net == 0) mu_out[b] = v;
    else          sig_out[b] = log1pf(__expf(v)) + 1e-4f;
  }
}

// ---------------- regularized incomplete beta (NR continued fraction) --------
__device__ float betacf_(float a, float b, float x)
{
  const float FPMIN = 1e-30f, EPS = 3e-7f;
  const float qab = a + b, qap = a + 1.f, qam = a - 1.f;
  float c = 1.f;
  float d = 1.f - qab * x / qap;
  if (fabsf(d) < FPMIN) d = FPMIN;
  d = 1.f / d;
  float h = d;
  for (int m = 1; m <= 100; ++m) {
    const float m2 = 2.f * m;
    float aa = m * (b - m) * x / ((qam + m2) * (a + m2));
    d = 1.f + aa * d; if (fabsf(d) < FPMIN) d = FPMIN;
    c = 1.f + aa / c; if (fabsf(c) < FPMIN) c = FPMIN;
    d = 1.f / d; h *= d * c;
    aa = -(a + m) * (qab + m) * x / ((a + m2) * (qap + m2));
    d = 1.f + aa * d; if (fabsf(d) < FPMIN) d = FPMIN;
    c = 1.f + aa / c; if (fabsf(c) < FPMIN) c = FPMIN;
    d = 1.f / d;
    const float del = d * c; h *= del;
    if (fabsf(del - 1.f) < EPS) break;
  }
  return h;
}

__device__ float betainc_(float a, float b, float x, float cx)
{
  if (x  <= 0.f) return 0.f;
  if (cx <= 0.f) return 1.f;
  const float lx  = (x  > 0.5f) ? log1pf(-cx) : logf(x);
  const float lcx = (cx > 0.5f) ? log1pf(-x)  : logf(cx);
  const float bt = expf(lgammaf(a+b) - lgammaf(a) - lgammaf(b) + a*lx + b*lcx);
  if (x < (a + 1.f) / (a + b + 2.f)) return bt * betacf_(a, b, x) / a;
  else                               return 1.f - bt * betacf_(b, a, cx) / b;
}

__global__ __launch_bounds__(256)
void stats_k(const float* __restrict__ mu, const float* __restrict__ sig,
             const float* __restrict__ dX, const float* __restrict__ dTp,
             const float* __restrict__ log_nu,
             float* __restrict__ cdf_out, float* __restrict__ parts)
{
  const int tid = threadIdx.x;
  const int b = blockIdx.x * 256 + tid;
  const float dT = dTp[0];
  const float df = fminf(fmaxf(expf(log_nu[0]), 2.1f), 30.0f);

  const float m = mu[b], s = sig[b];
  const float scale = s * sqrtf(dT);
  const float y  = (dX[b] - m * dT) / scale;
  const float y2 = y * y;
  const float lp = lgammaf((df + 1.f) * 0.5f) - lgammaf(df * 0.5f)
                 - 0.5f * logf(df * PI_F) - logf(scale)
                 - (df + 1.f) * 0.5f * log1pf(y2 / df);
  const float den = df + y2;
  const float xb = df / den, cxb = y2 / den;
  const float ib = betainc_(0.5f * df, 0.5f, xb, cxb);
  float cdf = (y <= 0.f) ? 0.5f * ib : 1.f - 0.5f * ib;
  cdf = fminf(fmaxf(cdf, 1e-6f), 1.f - 1e-6f);
  cdf_out[b] = cdf;

  __shared__ float red[256];
  red[tid] = lp; __syncthreads();
  for (int o = 128; o > 0; o >>= 1) { if (tid < o) red[tid] += red[tid + o]; __syncthreads(); }
  if (tid == 0) parts[blockIdx.x] = red[0];
  __syncthreads();
  red[tid] = cdf; __syncthreads();
  for (int o = 128; o > 0; o >>= 1) { if (tid < o) red[tid] += red[tid + o]; __syncthreads(); }
  if (tid == 0) parts[16 + blockIdx.x] = red[0];
  __syncthreads();
  red[tid] = cdf * cdf; __syncthreads();
  for (int o = 128; o > 0; o >>= 1) { if (tid < o) red[tid] += red[tid + o]; __syncthreads(); }
  if (tid == 0) parts[32 + blockIdx.x] = red[0];
}

// ---------------- KDE: one block per grid point -------------------------------
__global__ __launch_bounds__(256)
void kde_k(const float* __restrict__ cdf, const float* __restrict__ parts,
           float* __restrict__ pen)
{
  const int tid = threadIdx.x;
  float sc = 0.f, sc2 = 0.f;
  #pragma unroll
  for (int i = 0; i < 16; ++i) { sc += parts[16+i]; sc2 += parts[32+i]; }
  const float mean = sc / (float)Bn;
  const float var  = (sc2 - (float)Bn * mean * mean) / (float)(Bn - 1);
  const float sd   = sqrtf(fmaxf(var, 0.f));
  const float hbw  = 1.06f * sd * 0.18946457f + 1e-5f;   // 4096^-0.2
  const float inv  = 1.0f / hbw;
  const float u    = (float)blockIdx.x / (float)(NGRID - 1);
  const float c    = -0.5f * LOG2E;

  float acc = 0.f;
  for (int k = tid; k < Bn; k += 256) {
    const float d = (u - cdf[k]) * inv;
    acc += ex2(d * d * c);
  }
  __shared__ float sh[256];
  sh[tid] = acc; __syncthreads();
  for (int o = 128; o > 0; o >>= 1) { if (tid < o) sh[tid] += sh[tid + o]; __syncthreads(); }
  if (tid == 0) {
    const float f = sh[0] / (SQRT_2PI_F * (float)Bn * hbw);
    const float dd = f - 1.0f;
    pen[blockIdx.x] = dd * dd * (1.0f / (float)NGRID);
  }
}

__global__ __launch_bounds__(128)
void finish_k(const float* __restrict__ parts, const float* __restrict__ pen,
              float* __restrict__ out)
{
  const int tid = threadIdx.x;
  __shared__ float sh[128];
  sh[tid] = (tid < NGRID) ? pen[tid] : 0.f;
  __syncthreads();
  for (int o = 64; o > 0; o >>= 1) { if (tid < o) sh[tid] += sh[tid + o]; __syncthreads(); }
  if (tid == 0) {
    float slp = 0.f;
    #pragma unroll
    for (int i = 0; i < 16; ++i) slp += parts[i];
    out[0] = (-slp / (float)Bn) + 100.0f * sh[0];
  }
}

// ---------------- launcher ---------------------------------------------------
extern "C" void kernel_launch(void* const* d_in, const int* in_sizes, int n_in,
                              void* d_out, int out_size, void* d_ws, size_t ws_size,
                              hipStream_t stream)
{
  const float* x      = (const float*)d_in[0];
  const float* dX     = (const float*)d_in[1];
  const float* dT     = (const float*)d_in[2];
  const float* log_nu = (const float*)d_in[23];

  float* w     = (float*)d_ws;
  float* mu    = w;
  float* sig   = w + Bn;
  float* cdf   = w + 2 * Bn;
  float* parts = w + 3 * Bn;                    // 48 floats
  float* pen   = w + 3 * Bn + 48;               // 100 floats
  f16*  fragb  = (f16*)((char*)d_ws + 65536);   // 6 x 49152 halfs

  WSrc S;
  S.m[0] = (const float*)d_in[4];   // d_Whh0
  S.m[1] = (const float*)d_in[7];   // d_Wih1
  S.m[2] = (const float*)d_in[8];   // d_Whh1
  S.m[3] = (const float*)d_in[14];  // s_Whh0
  S.m[4] = (const float*)d_in[17];  // s_Wih1
  S.m[5] = (const float*)d_in[18];  // s_Whh1

  GruW Wd { fragb + (size_t)0*49152, fragb + (size_t)1*49152, fragb + (size_t)2*49152,
            (const float*)d_in[3], (const float*)d_in[5], (const float*)d_in[6],
            (const float*)d_in[9], (const float*)d_in[10],
            (const float*)d_in[11], (const float*)d_in[12] };
  GruW Ws { fragb + (size_t)3*49152, fragb + (size_t)4*49152, fragb + (size_t)5*49152,
            (const float*)d_in[13], (const float*)d_in[15], (const float*)d_in[16],
            (const float*)d_in[19], (const float*)d_in[20],
            (const float*)d_in[21], (const float*)d_in[22] };

  wconv_k <<<dim3(6*24), 256, 0, stream>>>(S, fragb);
  gru_mfma<<<dim3(512), 512, 0, stream>>>(x, Wd, Ws, mu, sig);
  stats_k <<<dim3(Bn/256), 256, 0, stream>>>(mu, sig, dX, dT, log_nu, cdf, parts);
  kde_k   <<<dim3(NGRID), 256, 0, stream>>>(cdf, parts, pen);
  finish_k<<<dim3(1), 128, 0, stream>>>(parts, pen, (float*)d_out);
}

// Round 10
// 128.213 us; speedup vs baseline: 1.5802x; 1.0952x over previous
//
#include <hip/hip_runtime.h>
#include <math.h>

#define Bn 4096
#define Tn 40
#define Hn 128
#define NGRID 100
#define PI_F 3.14159265358979f
#define SQRT_2PI_F 2.50662827f
#define LOG2E 1.44269504088896f

typedef _Float16 f16;
typedef __attribute__((ext_vector_type(8))) _Float16 f16x8;
typedef __attribute__((ext_vector_type(4))) float f32x4;

// MFMA with weight (B) operand pinned to AGPR class (gfx950 unified RF:
// MFMA reads B directly from AGPR). Weights load once -> AGPR-resident.
#define MFMA0(acc, va, wa) \
  asm("v_mfma_f32_16x16x32_f16 %0, %1, %2, 0" : "=v"(acc) : "v"(va), "a"(wa))
#define MFMA(acc, va, wa) \
  asm("v_mfma_f32_16x16x32_f16 %0, %1, %2, %0" : "+v"(acc) : "v"(va), "a"(wa))

struct GruW {
  const f16 *fWhh0, *fWih1, *fWhh1;     // fragment-layout fp16, gate-scaled
  const float *Wih0, *bih0, *bhh0, *bih1, *bhh1, *Wh, *bh;
};
struct WSrc { const float* m[6]; };

__device__ __forceinline__ float rcp_f(float x){ return __builtin_amdgcn_rcpf(x); }
__device__ __forceinline__ float ex2(float x){ return __builtin_amdgcn_exp2f(x); }
// LDS swizzle on byte bits 4..6: reads 2-way (free), writes conflict-free.
__device__ __forceinline__ int swz(int r){
  return ((r&1)<<4) | ((((r>>1)^(r>>3))&1)<<5) | ((r&4)<<4);
}

// ---- fp32 [384][128] -> fp16 MFMA-B fragment layout, pre-scaled per gate:
//      r,z rows (n<256): * -log2e ; n rows (n>=256): * 2*log2e
__global__ __launch_bounds__(256)
void wconv_k(WSrc S, f16* __restrict__ dst)
{
  const int m  = blockIdx.x / 24;
  const int nt = blockIdx.x % 24;
  const int ks = threadIdx.x >> 6;
  const int l  = threadIdx.x & 63;
  const float scale = (nt < 16) ? -LOG2E : (2.0f*LOG2E);
  const float* src = S.m[m] + (size_t)(nt*16 + (l&15))*Hn + ks*32 + (l>>4)*8;
  f16x8 o;
  #pragma unroll
  for (int jj = 0; jj < 8; ++jj) o[jj] = (f16)(src[jj] * scale);
  *((f16x8*)(dst + (size_t)m*49152) + ((nt*4 + ks)*64 + l)) = o;
}

// ---- fused 2-layer GRU: 32 rows/block, 256 blocks (one round), 8 waves,
//      weights AGPR-resident, h-state in f32 registers, two phases per step.
__global__ __launch_bounds__(512)
void gru_mfma(const float* __restrict__ x, GruW Wd, GruW Ws,
              float* __restrict__ mu_out, float* __restrict__ sig_out)
{
  const int net = blockIdx.x >> 7;
  const int r0  = (blockIdx.x & 127) * 32;
  const GruW W  = net ? Ws : Wd;
  const int tid = threadIdx.x;
  const int w   = tid >> 6;        // wave 0..7 -> gate-col block w*16..+15
  const int l   = tid & 63;

  __shared__ __align__(16) char smem[37888];
  char* const h0b0 = smem;                 // [32][128] f16, swizzled (8KB each)
  char* const h0b1 = smem + 8192;
  char* const h1b0 = smem + 16384;
  char* const h1b1 = smem + 24576;
  float* const xall = (float*)(smem + 32768);   // [32][40] f32

  for (int i = tid; i < 32*Tn; i += 512) xall[i] = x[(size_t)r0*Tn + i];
  ((int4*)h1b1)[tid] = make_int4(0,0,0,0);

  const int j = w*16 + (l & 15);   // hidden column 0..127
  const float wr_s = W.Wih0[j]      * (-LOG2E);
  const float wz_s = W.Wih0[Hn+j]   * (-LOG2E);
  const float wn_s = W.Wih0[2*Hn+j] * (2.0f*LOG2E);
  const float br0_s  = (W.bih0[j]      + W.bhh0[j])      * (-LOG2E);
  const float bz0_s  = (W.bih0[Hn+j]   + W.bhh0[Hn+j])   * (-LOG2E);
  const float bin0_s = W.bih0[2*Hn+j] * (2.0f*LOG2E);
  const float bnh0_s = W.bhh0[2*Hn+j] * (2.0f*LOG2E);
  const float br1_s  = (W.bih1[j]      + W.bhh1[j])      * (-LOG2E);
  const float bz1_s  = (W.bih1[Hn+j]   + W.bhh1[Hn+j])   * (-LOG2E);
  const float bin1_s = W.bih1[2*Hn+j] * (2.0f*LOG2E);
  const float bnh1_s = W.bhh1[2*Hn+j] * (2.0f*LOG2E);

  // weight fragments: every use is an 'a'-constrained MFMA operand -> AGPRs.
  const f16x8* F0  = (const f16x8*)W.fWhh0;
  const f16x8* F1i = (const f16x8*)W.fWih1;
  const f16x8* F1h = (const f16x8*)W.fWhh1;
  f16x8 w0[3][4], w1i[3][4], w1h[3][4];
  #pragma unroll
  for (int g = 0; g < 3; ++g)
    #pragma unroll
    for (int ks = 0; ks < 4; ++ks) {
      const int idx = ((w + 8*g)*4 + ks)*64 + l;
      w0[g][ks]  = F0[idx];
      w1i[g][ks] = F1i[idx];
      w1h[g][ks] = F1h[idx];
    }

  // A-frag read offsets (swizzled) and h write offsets
  int aoff[2][4], woff[2][4];
  {
    const int ar = l & 15, msk = swz(ar), acol = (l >> 4) * 16;
    #pragma unroll
    for (int mt = 0; mt < 2; ++mt)
      #pragma unroll
      for (int ks = 0; ks < 4; ++ks)
        aoff[mt][ks] = (mt*16 + ar)*256 + ((ks*64 + acol) ^ msk);
    #pragma unroll
    for (int mt = 0; mt < 2; ++mt)
      #pragma unroll
      for (int q = 0; q < 4; ++q) {
        const int row = mt*16 + (l>>4)*4 + q;
        woff[mt][q] = row*256 + ((2*j) ^ swz(row & 15));
      }
  }
  const int xb = (l>>4)*4*Tn;

  // f32 register h-state (exactly R8 numerics)
  float h0r[8], h1r[8] = {0,0,0,0,0,0,0,0}, s1r[8] = {0,0,0,0,0,0,0,0};

  __syncthreads();   // xall + h1b1 ready

  // ---- prologue: h0(0) from x(0) only (h0(-1)=0)
  #pragma unroll
  for (int mt = 0; mt < 2; ++mt)
    #pragma unroll
    for (int q = 0; q < 4; ++q) {
      const float xv = xall[xb + mt*16*Tn + q*Tn];
      const float rg = rcp_f(1.f + ex2(fmaf(xv, wr_s, br0_s)));
      const float zg = rcp_f(1.f + ex2(fmaf(xv, wz_s, bz0_s)));
      const float xn = fmaf(xv, wn_s, bin0_s);
      const float ng = fmaf(rcp_f(1.f + ex2(fmaf(rg, bnh0_s, xn))), -2.f, 1.f);
      const float hv = fmaf(-zg, ng, ng);
      h0r[mt*4+q] = hv;
      *(f16*)(h0b0 + woff[mt][q]) = (f16)hv;
    }
  __syncthreads();

  for (int i = 0; i < Tn; ++i) {
    const char* h0cur = (i&1) ? h0b1 : h0b0;
    char*       h0nxt = (i&1) ? h0b0 : h0b1;
    const char* h1prv = (i&1) ? h1b0 : h1b1;
    char*       h1cur = (i&1) ? h1b1 : h1b0;

    // ============ phase L0: gh0 = h0(i) @ Whh0^T -> h0(i+1) ============
    if (i < Tn-1) {
      f32x4 aR[2], aZ[2], aN[2];
      #pragma unroll
      for (int ks = 0; ks < 4; ++ks) {
        const f16x8 a0 = *(const f16x8*)(h0cur + aoff[0][ks]);
        const f16x8 a1 = *(const f16x8*)(h0cur + aoff[1][ks]);
        if (ks == 0) {
          MFMA0(aR[0], a0, w0[0][0]); MFMA0(aR[1], a1, w0[0][0]);
          MFMA0(aZ[0], a0, w0[1][0]); MFMA0(aZ[1], a1, w0[1][0]);
          MFMA0(aN[0], a0, w0[2][0]); MFMA0(aN[1], a1, w0[2][0]);
        } else {
          MFMA(aR[0], a0, w0[0][ks]); MFMA(aR[1], a1, w0[0][ks]);
          MFMA(aZ[0], a0, w0[1][ks]); MFMA(aZ[1], a1, w0[1][ks]);
          MFMA(aN[0], a0, w0[2][ks]); MFMA(aN[1], a1, w0[2][ks]);
        }
      }
      #pragma unroll
      for (int mt = 0; mt < 2; ++mt)
        #pragma unroll
        for (int q = 0; q < 4; ++q) {
          const int e = mt*4+q;
          const float xv = xall[xb + mt*16*Tn + q*Tn + i + 1];
          const float rg = rcp_f(1.f + ex2(fmaf(xv, wr_s, br0_s) + aR[mt][q]));
          const float zg = rcp_f(1.f + ex2(fmaf(xv, wz_s, bz0_s) + aZ[mt][q]));
          const float xn = fmaf(xv, wn_s, bin0_s);
          const float ng = fmaf(rcp_f(1.f + ex2(fmaf(rg, aN[mt][q] + bnh0_s, xn))), -2.f, 1.f);
          const float hv = fmaf(zg, h0r[e] - ng, ng);
          h0r[e] = hv;
          *(f16*)(h0nxt + woff[mt][q]) = (f16)hv;
        }
    }

    // ============ phase L1: h0(i)@Wih1^T + h1(i-1)@Whh1^T -> h1(i) ======
    {
      f32x4 aR[2], aZ[2], aXN[2], aHN[2];
      #pragma unroll
      for (int ks = 0; ks < 4; ++ks) {
        const f16x8 a0_0 = *(const f16x8*)(h0cur + aoff[0][ks]);
        const f16x8 a0_1 = *(const f16x8*)(h0cur + aoff[1][ks]);
        const f16x8 a1_0 = *(const f16x8*)(h1prv + aoff[0][ks]);
        const f16x8 a1_1 = *(const f16x8*)(h1prv + aoff[1][ks]);
        if (ks == 0) {
          MFMA0(aR[0],  a0_0, w1i[0][0]); MFMA0(aR[1],  a0_1, w1i[0][0]);
          MFMA (aR[0],  a1_0, w1h[0][0]); MFMA (aR[1],  a1_1, w1h[0][0]);
          MFMA0(aZ[0],  a0_0, w1i[1][0]); MFMA0(aZ[1],  a0_1, w1i[1][0]);
          MFMA (aZ[0],  a1_0, w1h[1][0]); MFMA (aZ[1],  a1_1, w1h[1][0]);
          MFMA0(aXN[0], a0_0, w1i[2][0]); MFMA0(aXN[1], a0_1, w1i[2][0]);
          MFMA0(aHN[0], a1_0, w1h[2][0]); MFMA0(aHN[1], a1_1, w1h[2][0]);
        } else {
          MFMA(aR[0],  a0_0, w1i[0][ks]); MFMA(aR[1],  a0_1, w1i[0][ks]);
          MFMA(aR[0],  a1_0, w1h[0][ks]); MFMA(aR[1],  a1_1, w1h[0][ks]);
          MFMA(aZ[0],  a0_0, w1i[1][ks]); MFMA(aZ[1],  a0_1, w1i[1][ks]);
          MFMA(aZ[0],  a1_0, w1h[1][ks]); MFMA(aZ[1],  a1_1, w1h[1][ks]);
          MFMA(aXN[0], a0_0, w1i[2][ks]); MFMA(aXN[1], a0_1, w1i[2][ks]);
          MFMA(aHN[0], a1_0, w1h[2][ks]); MFMA(aHN[1], a1_1, w1h[2][ks]);
        }
      }
      #pragma unroll
      for (int mt = 0; mt < 2; ++mt)
        #pragma unroll
        for (int q = 0; q < 4; ++q) {
          const int e = mt*4+q;
          const float rg = rcp_f(1.f + ex2(aR[mt][q] + br1_s));
          const float zg = rcp_f(1.f + ex2(aZ[mt][q] + bz1_s));
          const float ng = fmaf(rcp_f(1.f + ex2(fmaf(rg, aHN[mt][q] + bnh1_s, aXN[mt][q] + bin1_s))), -2.f, 1.f);
          const float hv = fmaf(zg, h1r[e] - ng, ng);
          h1r[e] = hv;
          s1r[e] += hv;
          *(f16*)(h1cur + woff[mt][q]) = (f16)hv;
        }
    }
    __syncthreads();   // single barrier per step
  }

  // ---- head: p[row] = h0.WhA + h1.WhB + mean_t(s1).WhC, reduce over j
  const float whA = W.Wh[j], whB = W.Wh[Hn+j], whC = W.Wh[2*Hn+j] * (1.0f/Tn);
  float* hredf = (float*)xall;    // reuse dead x buffer: [32][8]
  __syncthreads();
  #pragma unroll
  for (int mt = 0; mt < 2; ++mt)
    #pragma unroll
    for (int q = 0; q < 4; ++q) {
      const int e = mt*4+q;
      float p = h0r[e]*whA + h1r[e]*whB + s1r[e]*whC;
      p += __shfl_xor(p, 1); p += __shfl_xor(p, 2);
      p += __shfl_xor(p, 4); p += __shfl_xor(p, 8);
      if ((l & 15) == 0) hredf[(mt*16 + (l>>4)*4 + q)*8 + w] = p;
    }
  __syncthreads();
  if (tid < 32) {
    float s = W.bh[0];
    #pragma unroll
    for (int ww = 0; ww < 8; ++ww) s += hredf[tid*8 + ww];
    const float v = fminf(fmaxf(s, -20.f), 20.f);
    const int b = r0 + tid;
    if (net == 0) mu_out[b] = v;
    else          sig_out[b] = log1pf(__expf(v)) + 1e-4f;
  }
}

// ---------------- regularized incomplete beta (NR continued fraction) --------
__device__ float betacf_(float a, float b, float x)
{
  const float FPMIN = 1e-30f, EPS = 3e-7f;
  const float qab = a + b, qap = a + 1.f, qam = a - 1.f;
  float c = 1.f;
  float d = 1.f - qab * x / qap;
  if (fabsf(d) < FPMIN) d = FPMIN;
  d = 1.f / d;
  float h = d;
  for (int m = 1; m <= 100; ++m) {
    const float m2 = 2.f * m;
    float aa = m * (b - m) * x / ((qam + m2) * (a + m2));
    d = 1.f + aa * d; if (fabsf(d) < FPMIN) d = FPMIN;
    c = 1.f + aa / c; if (fabsf(c) < FPMIN) c = FPMIN;
    d = 1.f / d; h *= d * c;
    aa = -(a + m) * (qab + m) * x / ((a + m2) * (qap + m2));
    d = 1.f + aa * d; if (fabsf(d) < FPMIN) d = FPMIN;
    c = 1.f + aa / c; if (fabsf(c) < FPMIN) c = FPMIN;
    d = 1.f / d;
    const float del = d * c; h *= del;
    if (fabsf(del - 1.f) < EPS) break;
  }
  return h;
}

__device__ float betainc_(float a, float b, float x, float cx)
{
  if (x  <= 0.f) return 0.f;
  if (cx <= 0.f) return 1.f;
  const float lx  = (x  > 0.5f) ? log1pf(-cx) : logf(x);
  const float lcx = (cx > 0.5f) ? log1pf(-x)  : logf(cx);
  const float bt = expf(lgammaf(a+b) - lgammaf(a) - lgammaf(b) + a*lx + b*lcx);
  if (x < (a + 1.f) / (a + b + 2.f)) return bt * betacf_(a, b, x) / a;
  else                               return 1.f - bt * betacf_(b, a, cx) / b;
}

__global__ __launch_bounds__(256)
void stats_k(const float* __restrict__ mu, const float* __restrict__ sig,
             const float* __restrict__ dX, const float* __restrict__ dTp,
             const float* __restrict__ log_nu,
             float* __restrict__ cdf_out, float* __restrict__ parts)
{
  const int tid = threadIdx.x;
  const int b = blockIdx.x * 256 + tid;
  const float dT = dTp[0];
  const float df = fminf(fmaxf(expf(log_nu[0]), 2.1f), 30.0f);

  const float m = mu[b], s = sig[b];
  const float scale = s * sqrtf(dT);
  const float y  = (dX[b] - m * dT) / scale;
  const float y2 = y * y;
  const float lp = lgammaf((df + 1.f) * 0.5f) - lgammaf(df * 0.5f)
                 - 0.5f * logf(df * PI_F) - logf(scale)
                 - (df + 1.f) * 0.5f * log1pf(y2 / df);
  const float den = df + y2;
  const float xb = df / den, cxb = y2 / den;
  const float ib = betainc_(0.5f * df, 0.5f, xb, cxb);
  float cdf = (y <= 0.f) ? 0.5f * ib : 1.f - 0.5f * ib;
  cdf = fminf(fmaxf(cdf, 1e-6f), 1.f - 1e-6f);
  cdf_out[b] = cdf;

  __shared__ float red[256];
  red[tid] = lp; __syncthreads();
  for (int o = 128; o > 0; o >>= 1) { if (tid < o) red[tid] += red[tid + o]; __syncthreads(); }
  if (tid == 0) parts[blockIdx.x] = red[0];
  __syncthreads();
  red[tid] = cdf; __syncthreads();
  for (int o = 128; o > 0; o >>= 1) { if (tid < o) red[tid] += red[tid + o]; __syncthreads(); }
  if (tid == 0) parts[16 + blockIdx.x] = red[0];
  __syncthreads();
  red[tid] = cdf * cdf; __syncthreads();
  for (int o = 128; o > 0; o >>= 1) { if (tid < o) red[tid] += red[tid + o]; __syncthreads(); }
  if (tid == 0) parts[32 + blockIdx.x] = red[0];
}

// ---------------- KDE: one block per grid point -------------------------------
__global__ __launch_bounds__(256)
void kde_k(const float* __restrict__ cdf, const float* __restrict__ parts,
           float* __restrict__ pen)
{
  const int tid = threadIdx.x;
  float sc = 0.f, sc2 = 0.f;
  #pragma unroll
  for (int i = 0; i < 16; ++i) { sc += parts[16+i]; sc2 += parts[32+i]; }
  const float mean = sc / (float)Bn;
  const float var  = (sc2 - (float)Bn * mean * mean) / (float)(Bn - 1);
  const float sd   = sqrtf(fmaxf(var, 0.f));
  const float hbw  = 1.06f * sd * 0.18946457f + 1e-5f;   // 4096^-0.2
  const float inv  = 1.0f / hbw;
  const float u    = (float)blockIdx.x / (float)(NGRID - 1);
  const float c    = -0.5f * LOG2E;

  float acc = 0.f;
  for (int k = tid; k < Bn; k += 256) {
    const float d = (u - cdf[k]) * inv;
    acc += ex2(d * d * c);
  }
  __shared__ float sh[256];
  sh[tid] = acc; __syncthreads();
  for (int o = 128; o > 0; o >>= 1) { if (tid < o) sh[tid] += sh[tid + o]; __syncthreads(); }
  if (tid == 0) {
    const float f = sh[0] / (SQRT_2PI_F * (float)Bn * hbw);
    const float dd = f - 1.0f;
    pen[blockIdx.x] = dd * dd * (1.0f / (float)NGRID);
  }
}

__global__ __launch_bounds__(128)
void finish_k(const float* __restrict__ parts, const float* __restrict__ pen,
              float* __restrict__ out)
{
  const int tid = threadIdx.x;
  __shared__ float sh[128];
  sh[tid] = (tid < NGRID) ? pen[tid] : 0.f;
  __syncthreads();
  for (int o = 64; o > 0; o >>= 1) { if (tid < o) sh[tid] += sh[tid + o]; __syncthreads(); }
  if (tid == 0) {
    float slp = 0.f;
    #pragma unroll
    for (int i = 0; i < 16; ++i) slp += parts[i];
    out[0] = (-slp / (float)Bn) + 100.0f * sh[0];
  }
}

// ---------------- launcher ---------------------------------------------------
extern "C" void kernel_launch(void* const* d_in, const int* in_sizes, int n_in,
                              void* d_out, int out_size, void* d_ws, size_t ws_size,
                              hipStream_t stream)
{
  const float* x      = (const float*)d_in[0];
  const float* dX     = (const float*)d_in[1];
  const float* dT     = (const float*)d_in[2];
  const float* log_nu = (const float*)d_in[23];

  float* w     = (float*)d_ws;
  float* mu    = w;
  float* sig   = w + Bn;
  float* cdf   = w + 2 * Bn;
  float* parts = w + 3 * Bn;                    // 48 floats
  float* pen   = w + 3 * Bn + 48;               // 100 floats
  f16*  fragb  = (f16*)((char*)d_ws + 65536);   // 6 x 49152 halfs

  WSrc S;
  S.m[0] = (const float*)d_in[4];   // d_Whh0
  S.m[1] = (const float*)d_in[7];   // d_Wih1
  S.m[2] = (const float*)d_in[8];   // d_Whh1
  S.m[3] = (const float*)d_in[14];  // s_Whh0
  S.m[4] = (const float*)d_in[17];  // s_Wih1
  S.m[5] = (const float*)d_in[18];  // s_Whh1

  GruW Wd { fragb + (size_t)0*49152, fragb + (size_t)1*49152, fragb + (size_t)2*49152,
            (const float*)d_in[3], (const float*)d_in[5], (const float*)d_in[6],
            (const float*)d_in[9], (const float*)d_in[10],
            (const float*)d_in[11], (const float*)d_in[12] };
  GruW Ws { fragb + (size_t)3*49152, fragb + (size_t)4*49152, fragb + (size_t)5*49152,
            (const float*)d_in[13], (const float*)d_in[15], (const float*)d_in[16],
            (const float*)d_in[19], (const float*)d_in[20],
            (const float*)d_in[21], (const float*)d_in[22] };

  wconv_k <<<dim3(6*24), 256, 0, stream>>>(S, fragb);
  gru_mfma<<<dim3(256), 512, 0, stream>>>(x, Wd, Ws, mu, sig);
  stats_k <<<dim3(Bn/256), 256, 0, stream>>>(mu, sig, dX, dT, log_nu, cdf, parts);
  kde_k   <<<dim3(NGRID), 256, 0, stream>>>(cdf, parts, pen);
  finish_k<<<dim3(1), 128, 0, stream>>>(parts, pen, (float*)d_out);
}